// Round 20
// baseline (24.687 us; speedup 1.0000x reference)
//
#include <hip/hip_runtime.h>
#include <math.h>

typedef __fp16 h2 __attribute__((ext_vector_type(2)));
typedef float  f4 __attribute__((ext_vector_type(4)));   // native vec for nt-store

#define H_IN   136
#define W_IN   200
#define HWP    (H_IN * W_IN)       // 27200
#define OH     272
#define OW     400
#define RB     8                   // low-res rows per strip (17 strips)
#define NSTRIP 17
#define LROWS  (RB + 1)            // +1 halo row above
#define CH     8
#define CIN    8
#define NPARAM 169
#define NEG_LOG2E (-1.4426950408889634f)

// R20 = R19 base (fp16 MLP, hoisted loads, nt stores) + intra-block phase
// interleave (R11 structure, retested in the new regime):
//   P1a(T 0..4) | bar | {P1b loads -> P2a(out rows 0..7) -> P1b MLP(T 5..8)}
//   | bar | P2b(out rows 8..15)
// Rationale: grid is ~fully co-resident, so chip-wide phases alternate as
// synchronized VALU-epochs and store-epochs; interleaving fills both pipes.
// P1b's global loads issue BEFORE P2a's stores (latency hides under them).
// Per-pixel math identical -> absmax canary 0.00390625.

__device__ __forceinline__ h2 pkrtz(float a, float b) {
    return __builtin_amdgcn_cvt_pkrtz(a, b);
}

__device__ __forceinline__ void nt_store4(float* p, float4 v) {
    f4 nv = {v.x, v.y, v.z, v.w};
    __builtin_nontemporal_store(nv, (f4*)p);
}

// 4-px fp16 MLP (feats pre-loaded); returns t-space logits for px c..c+3
__device__ __forceinline__ float4 mlp4h(const h2* sW, const float4* fv,
                                        float loc_x, float loc_y, float inv_soi,
                                        int r, int c)
{
    h2 f[CIN][2];
    #pragma unroll
    for (int ch = 0; ch < CIN; ++ch) {
        f[ch][0] = pkrtz(fv[ch].x, fv[ch].y);
        f[ch][1] = pkrtz(fv[ch].z, fv[ch].w);
    }
    const float ry  = (loc_y - (float)(r * 8 + 4)) * inv_soi;
    const float dx  = -8.0f * inv_soi;
    const float rx0 = (loc_x - (float)(c * 8 + 4)) * inv_soi;
    h2 rxh[2];
    rxh[0] = pkrtz(rx0, rx0 + dx);
    rxh[1] = pkrtz(rx0 + 2.0f * dx, rx0 + 3.0f * dx);
    const h2 ryh = pkrtz(ry, ry);
    const h2 z2  = {(__fp16)0.0f, (__fp16)0.0f};

    h2 h0[CH][2];
    #pragma unroll
    for (int o = 0; o < CH; ++o) {
        const h2 base = __builtin_elementwise_fma(sW[o * 10 + 1], ryh, sW[152 + o]);
        const h2 wx = sW[o * 10];
        h2 a0 = __builtin_elementwise_fma(wx, rxh[0], base);
        h2 a1 = __builtin_elementwise_fma(wx, rxh[1], base);
        #pragma unroll
        for (int i = 0; i < CIN; ++i) {
            const h2 w = sW[o * 10 + 2 + i];
            a0 = __builtin_elementwise_fma(w, f[i][0], a0);
            a1 = __builtin_elementwise_fma(w, f[i][1], a1);
        }
        h0[o][0] = __builtin_elementwise_max(a0, z2);
        h0[o][1] = __builtin_elementwise_max(a1, z2);
    }
    h2 h1[CH][2];
    #pragma unroll
    for (int o = 0; o < CH; ++o) {
        const h2 b = sW[160 + o];
        h2 a0 = b, a1 = b;
        #pragma unroll
        for (int i = 0; i < CH; ++i) {
            const h2 w = sW[80 + o * CH + i];
            a0 = __builtin_elementwise_fma(w, h0[i][0], a0);
            a1 = __builtin_elementwise_fma(w, h0[i][1], a1);
        }
        h1[o][0] = __builtin_elementwise_max(a0, z2);
        h1[o][1] = __builtin_elementwise_max(a1, z2);
    }
    const h2 b2 = sW[168];
    h2 t0 = b2, t1 = b2;
    #pragma unroll
    for (int i = 0; i < CH; ++i) {
        const h2 w = sW[144 + i];
        t0 = __builtin_elementwise_fma(w, h1[i][0], t0);
        t1 = __builtin_elementwise_fma(w, h1[i][1], t1);
    }
    return make_float4((float)t0.x, (float)t0.y, (float)t1.x, (float)t1.y);
}

// 16-px aligned-bilinear upsample + sigmoid (8 wide x 2 output rows), nt stores
__device__ __forceinline__ void upsample16(
    const float (*T)[W_IN], float* __restrict__ O, int r0, int rpl, int t)
{
    const int cm = 4 * t;
    const int cl = max(cm - 1, 0);

    const float4 mR = *(const float4*)&T[rpl + 1][cm];
    const float4 mQ = *(const float4*)&T[rpl][cm];
    const float  AR = T[rpl + 1][cl];       // == mR.x when t==0
    const float  AQ = T[rpl][cl];

    const float Aa = 0.5f * (AR + AQ);
    const float Ba = 0.5f * (mR.x + mQ.x);
    const float Ca = 0.5f * (mR.y + mQ.y);
    const float Da = 0.5f * (mR.z + mQ.z);
    const float Ea = 0.5f * (mR.w + mQ.w);

    float4 s0, s1, s2, s3;
    s0.x = __builtin_amdgcn_rcpf(1.0f + __builtin_amdgcn_exp2f(0.5f * (Aa + Ba)));
    s0.y = __builtin_amdgcn_rcpf(1.0f + __builtin_amdgcn_exp2f(Ba));
    s0.z = __builtin_amdgcn_rcpf(1.0f + __builtin_amdgcn_exp2f(0.5f * (Ba + Ca)));
    s0.w = __builtin_amdgcn_rcpf(1.0f + __builtin_amdgcn_exp2f(Ca));
    s1.x = __builtin_amdgcn_rcpf(1.0f + __builtin_amdgcn_exp2f(0.5f * (Ca + Da)));
    s1.y = __builtin_amdgcn_rcpf(1.0f + __builtin_amdgcn_exp2f(Da));
    s1.z = __builtin_amdgcn_rcpf(1.0f + __builtin_amdgcn_exp2f(0.5f * (Da + Ea)));
    s1.w = __builtin_amdgcn_rcpf(1.0f + __builtin_amdgcn_exp2f(Ea));

    s2.x = __builtin_amdgcn_rcpf(1.0f + __builtin_amdgcn_exp2f(0.5f * (AR + mR.x)));
    s2.y = __builtin_amdgcn_rcpf(1.0f + __builtin_amdgcn_exp2f(mR.x));
    s2.z = __builtin_amdgcn_rcpf(1.0f + __builtin_amdgcn_exp2f(0.5f * (mR.x + mR.y)));
    s2.w = __builtin_amdgcn_rcpf(1.0f + __builtin_amdgcn_exp2f(mR.y));
    s3.x = __builtin_amdgcn_rcpf(1.0f + __builtin_amdgcn_exp2f(0.5f * (mR.y + mR.z)));
    s3.y = __builtin_amdgcn_rcpf(1.0f + __builtin_amdgcn_exp2f(mR.z));
    s3.z = __builtin_amdgcn_rcpf(1.0f + __builtin_amdgcn_exp2f(0.5f * (mR.z + mR.w)));
    s3.w = __builtin_amdgcn_rcpf(1.0f + __builtin_amdgcn_exp2f(mR.w));

    float* O0 = O + (size_t)(2 * (r0 + rpl)) * OW + 8 * t;
    nt_store4(O0,          s0);
    nt_store4(O0 + 4,      s1);
    nt_store4(O0 + OW,     s2);
    nt_store4(O0 + OW + 4, s3);
}

__global__ __launch_bounds__(256, 3) void mask_head_fused(
    const float* __restrict__ mask_feats,   // (N, 8, H, W)
    const float* __restrict__ params,       // (n_inst, 169)
    const float* __restrict__ locations,    // (n_inst, 2)
    const int*   __restrict__ im_inds,      // (n_inst,)
    const int*   __restrict__ fpn_levels,   // (n_inst,)
    const float* __restrict__ soi_tab,      // (5,)
    float* __restrict__ out)                // (n_inst, 272, 400)
{
    __shared__ h2    sW[NPARAM];            // packed (dup) fp16 weights
    __shared__ float T[LROWS][W_IN];        // t = -log2e * logit

    const int inst = blockIdx.y;
    const int r0   = blockIdx.x * RB;
    const int tid  = threadIdx.x;

    const float* F = mask_feats + (size_t)im_inds[inst] * (CIN * HWP);

    // ---- hoisted P1a feature loads (T slots 0..4: rows r0-1..r0+3) ----
    const int  ka = tid / 50;
    const int  ca = (tid - ka * 50) * 4;
    const int  ra = min(max(r0 - 1 + ka, 0), H_IN - 1);
    const bool p1a = (tid < 5 * 50);

    float4 fa[CIN];
    if (p1a) {
        #pragma unroll
        for (int ch = 0; ch < CIN; ++ch)
            fa[ch] = *(const float4*)(F + ch * HWP + ra * W_IN + ca);
    }

    // ---- weight staging overlaps in-flight loads ----
    const float* P = params + inst * NPARAM;
    if (tid < NPARAM) {
        float w = P[tid];
        if ((tid >= 144 && tid < 152) || tid == 168) w *= NEG_LOG2E;
        const __fp16 hw = (__fp16)w;
        h2 v; v.x = hw; v.y = hw;
        sW[tid] = v;
    }

    const float loc_x   = locations[2 * inst];
    const float loc_y   = locations[2 * inst + 1];
    const float inv_soi = 1.0f / soi_tab[fpn_levels[inst]];
    float* O = out + (size_t)inst * (OH * OW);
    __syncthreads();

    // ---- P1a: 250 units x 4 px -> T[0..4] ----
    if (p1a)
        *(float4*)&T[ka][ca] = mlp4h(sW, fa, loc_x, loc_y, inv_soi, ra, ca);
    __syncthreads();

    // ---- mixed epoch: P1b loads -> P2a (stores) -> P1b MLP ----
    const bool pb = (tid < 200);
    const int  kb = 5 + tid / 50;                   // T slot 5..8
    const int  cb = (tid - (tid / 50) * 50) * 4;
    const int  rb = min(r0 - 1 + kb, H_IN - 1);     // rows r0+4..r0+7

    float4 fb[CIN];
    if (pb) {
        #pragma unroll
        for (int ch = 0; ch < CIN; ++ch)
            fb[ch] = *(const float4*)(F + ch * HWP + rb * W_IN + cb);
    }
    if (pb)                                          // out rows 2r0..2r0+7
        upsample16(T, O, r0, tid / 50, tid % 50);    // reads T[0..4]
    if (pb)                                          // writes T[5..8] (disjoint)
        *(float4*)&T[kb][cb] = mlp4h(sW, fb, loc_x, loc_y, inv_soi, rb, cb);
    __syncthreads();

    // ---- P2b: out rows 2r0+8..2r0+15, reads T[4..8] ----
    if (pb)
        upsample16(T, O, r0, 4 + tid / 50, tid % 50);
}

extern "C" void kernel_launch(void* const* d_in, const int* in_sizes, int n_in,
                              void* d_out, int out_size, void* d_ws, size_t ws_size,
                              hipStream_t stream) {
    const float* mask_feats = (const float*)d_in[0];
    const float* params     = (const float*)d_in[1];
    const float* locations  = (const float*)d_in[2];
    const int*   im_inds    = (const int*)d_in[3];
    const int*   fpn_levels = (const int*)d_in[4];
    const float* soi_tab    = (const float*)d_in[5];

    const int n_inst = in_sizes[1] / NPARAM;   // 128
    dim3 grid(NSTRIP, n_inst);                 // (17, 128)
    mask_head_fused<<<grid, 256, 0, stream>>>(
        mask_feats, params, locations, im_inds, fpn_levels, soi_tab, (float*)d_out);
}